// Round 3
// 863.074 us; speedup vs baseline: 1.1048x; 1.1048x over previous
//
#include <hip/hip_runtime.h>
#include <stdint.h>
#include <stddef.h>

// ---------------- problem constants ----------------
#define BATCH 8
#define NPT   2048
#define NB    (BATCH*NPT)            // 16384
#define CAP   128                    // max sparse entries per row/col
#define ITERS 100
#define TPB   1024
#define NWAVE (TPB/64)
#define C50      1.9287498479639178e-22f   // expf(-50.f) == clamp floor of K
#define MUV      (1.0f/2048.0f)
#define EPS_DIVF 1e-8f

// ---------------- workspace layout (bytes), 16B-aligned ----------------
// cnt is u16 to make room for the inverse permutation at zero net cost.
#define OFF_GMAX 0u                                   // gmax[dir][b*32+g], 2 KB used
#define OFF_CNT  4096u                                // u16 cnt[dir][b][n], 64 KB
#define OFF_PERM (OFF_CNT  + (size_t)2*NB*2)          // u16 perm[dir][b][p], 64 KB (pos -> orig)
#define OFF_IPRM (OFF_PERM + (size_t)2*NB*2)          // u16 inv [dir][b][n], 64 KB (orig -> pos)
#define OFF_SPTS (OFF_IPRM + (size_t)2*NB*2)          // float4, 256 KB (== 200704, same as baseline)
#define OFF_TPTS (OFF_SPTS + (size_t)NB*16)
#define OFF_U    (OFF_TPTS + (size_t)NB*16)
#define OFF_V    (OFF_U + (size_t)NB*4)
#define OFF_ROWE (OFF_V + (size_t)NB*4)               // ELL-T4 slab (sorted rows), 8 MB
#define OFF_COLE (OFF_ROWE + (size_t)NB*CAP*4)        // 8 MB
// total 17,633,280 B — identical to the previously-passing layout

// Pack (K - C50): keep 12 mantissa bits (round-to-nearest), low 11 bits = column index
// (column index stored in SORTED space of the opposite direction).
__device__ __forceinline__ uint32_t pack_entry(float kv, int idx) {
    uint32_t bb = __float_as_uint(kv);
    bb = (bb + 0x400u) & 0xFFFFF800u;
    return bb | (uint32_t)idx;
}

// ELL-T4 address of entry `ofs` of sorted-row `p` within a batch slab (dword units)
__device__ __forceinline__ size_t ellt4_addr(int ofs, int p) {
    return (size_t)(ofs >> 2) * (NPT*4) + (size_t)p * 4 + (ofs & 3);
}

// ========== kernel A: stage float4 points + per-row/col entry counts ==========
extern "C" __global__ __launch_bounds__(TPB, 2)
void emd_count_56831007261025(const float* __restrict__ src,
                              const float* __restrict__ tgt,
                              uint8_t* __restrict__ wsb,
                              float* __restrict__ out)
{
    __shared__ float4 opts[NPT];

    uint16_t* cnt   = (uint16_t*)(wsb + OFF_CNT);
    float4*   gspts = (float4*)  (wsb + OFF_SPTS);
    float4*   gtpts = (float4*)  (wsb + OFF_TPTS);

    const int tid  = threadIdx.x;
    const int lane = tid & 63;
    const int wid  = tid >> 6;
    const int b    = blockIdx.x >> 5;
    const int g    = blockIdx.x & 31;
    const size_t base = (size_t)b * NPT;

    if (blockIdx.x == 0 && tid == 0) *out = 0.0f;

    if (tid < 64) {
        size_t gi = base + g*64 + tid;
        gspts[gi] = make_float4(src[3*gi], src[3*gi+1], src[3*gi+2], 0.0f);
        gtpts[gi] = make_float4(tgt[3*gi], tgt[3*gi+1], tgt[3*gi+2], 0.0f);
    }

    for (int pass = 0; pass < 2; ++pass) {
        const float* mineRaw  = pass ? tgt : src;
        const float* cloudRaw = pass ? src : tgt;

        __syncthreads();
        for (int i = tid; i < NPT; i += TPB) {
            size_t gi = base + i;
            opts[i] = make_float4(cloudRaw[3*gi], cloudRaw[3*gi+1], cloudRaw[3*gi+2], 0.0f);
        }
        __syncthreads();

        for (int r = 0; r < 4; ++r) {
            int n = g*64 + wid*4 + r;
            size_t gi = base + n;
            float4 sp = make_float4(mineRaw[3*gi], mineRaw[3*gi+1], mineRaw[3*gi+2], 0.0f);
            uint32_t c = 0;
            for (int mb = 0; mb < NPT; mb += 64) {
                float4 tp = opts[mb + lane];
                float dx = sp.x - tp.x, dy = sp.y - tp.y, dz = sp.z - tp.z;
                float d2 = dx*dx + dy*dy + dz*dz;
                c += (uint32_t)__popcll(__ballot(d2 < 0.25f));
            }
            if (lane == 0) cnt[(size_t)pass*NB + gi] = (uint16_t)((c < CAP) ? c : CAP);
        }
    }
}

// ========== kernel B: counting-sort rows by count, per (dir, batch); emit inverse perm ==========
extern "C" __global__ __launch_bounds__(256, 4)
void emd_sort_56831007261025(uint8_t* __restrict__ wsb)
{
    __shared__ uint32_t hist[CAP+2];
    __shared__ uint32_t bofs[CAP+2];
    __shared__ uint16_t permL[NPT];

    const int tid = threadIdx.x;
    const int dir = blockIdx.x >> 3;
    const int b   = blockIdx.x & 7;

    const uint16_t* cnt  = (const uint16_t*)(wsb + OFF_CNT) + (size_t)dir*NB + (size_t)b*NPT;
    uint16_t*       perm = (uint16_t*)(wsb + OFF_PERM) + (size_t)dir*NB + (size_t)b*NPT;
    uint16_t*       inv  = (uint16_t*)(wsb + OFF_IPRM) + (size_t)dir*NB + (size_t)b*NPT;
    uint32_t*       gmax = (uint32_t*)(wsb + OFF_GMAX) + (size_t)dir*256 + (size_t)b*32;

    for (int i = tid; i < CAP+2; i += 256) hist[i] = 0;
    __syncthreads();
    for (int n = tid; n < NPT; n += 256) atomicAdd(&hist[cnt[n]], 1u);
    __syncthreads();
    if (tid == 0) {
        uint32_t run = 0;
        for (int i = 0; i < CAP+2; ++i) { bofs[i] = run; run += hist[i]; }
    }
    __syncthreads();
    for (int n = tid; n < NPT; n += 256) {
        uint32_t p = atomicAdd(&bofs[cnt[n]], 1u);
        permL[p] = (uint16_t)n;
    }
    __syncthreads();
    for (int p = tid; p < NPT; p += 256) {
        uint16_t o = permL[p];
        perm[p] = o;
        inv[o]  = (uint16_t)p;
    }
    if (tid < 32) gmax[tid] = cnt[permL[tid*64 + 63]];   // sorted ascending -> group max
}

// ========== kernel C: build ELL-T4 slabs; columns pre-mapped into sorted space ==========
extern "C" __global__ __launch_bounds__(TPB, 2)
void emd_build_56831007261025(uint8_t* __restrict__ wsb)
{
    __shared__ float4   opts[NPT];
    __shared__ uint16_t rows[64];
    __shared__ uint16_t invp[NPT];     // orig col -> sorted pos of OPPOSITE direction

    const float4* gspts = (const float4*)(wsb + OFF_SPTS);
    const float4* gtpts = (const float4*)(wsb + OFF_TPTS);
    uint32_t*     rowE  = (uint32_t*)(wsb + OFF_ROWE);
    uint32_t*     colE  = (uint32_t*)(wsb + OFF_COLE);

    const int tid  = threadIdx.x;
    const int lane = tid & 63;
    const int wid  = tid >> 6;
    const int b    = blockIdx.x >> 5;
    const int g    = blockIdx.x & 31;
    const size_t base  = (size_t)b * NPT;
    const size_t ebase = (size_t)b * NPT * CAP;

    // zero-fill this block's sorted-row slice in both slabs (padding entries == 0)
    for (int idx = tid; idx < 32*256; idx += TPB) {
        int j4 = idx >> 8, t = idx & 255;
        size_t a = ebase + (size_t)j4*(NPT*4) + (size_t)g*256 + t;
        rowE[a] = 0u;
        colE[a] = 0u;
    }

    for (int pass = 0; pass < 2; ++pass) {
        const float4* mine  = pass ? gtpts : gspts;
        const float4* cloud = pass ? gspts : gtpts;
        uint32_t*     E     = pass ? colE : rowE;
        const uint16_t* permG = (const uint16_t*)(wsb + OFF_PERM) + (size_t)pass*NB + base;
        const uint16_t* invG  = (const uint16_t*)(wsb + OFF_IPRM) + (size_t)(1-pass)*NB + base;

        __syncthreads();
        for (int i = tid; i < NPT; i += TPB) {
            opts[i] = cloud[base + i];
            invp[i] = invG[i];
        }
        if (tid < 64) rows[tid] = permG[g*64 + tid];
        __syncthreads();

        for (int r = 0; r < 4; ++r) {
            int psort = g*64 + wid*4 + r;              // sorted position (slab row)
            int n     = rows[wid*4 + r];               // original row
            float4 sp = mine[base + n];
            uint32_t c = 0;
            for (int mb = 0; mb < NPT; mb += 64) {
                int m = mb + lane;
                float4 tp = opts[m];
                float dx = sp.x - tp.x, dy = sp.y - tp.y, dz = sp.z - tp.z;
                float d2 = dx*dx + dy*dy + dz*dz;
                bool p = d2 < 0.25f;
                uint64_t mask = __ballot(p);
                uint32_t ofs = c + (uint32_t)__popcll(mask & ((1ull << lane) - 1ull));
                if (p && ofs < CAP) {
                    float d  = sqrtf(d2);
                    float kv = expf(-100.0f * d) - C50;
                    E[ebase + ellt4_addr((int)ofs, psort)] = pack_entry(kv, invp[m]);
                }
                c += (uint32_t)__popcll(mask);
            }
        }
    }
}

// ========== kernel D: 100 Sinkhorn iterations, one block per batch ==========
__device__ __forceinline__ uint4 ldE(const uint32_t* ep, int j4) {
    return *(const uint4*)(ep + (size_t)j4 * (NPT*4));   // coalesced 1KB per (group, j4)
}

#define FMA4(acc, e4, W) do { \
    acc = fmaf(__uint_as_float((e4).x & 0xFFFFF800u), W[(e4).x & 0x7FFu], acc); \
    acc = fmaf(__uint_as_float((e4).y & 0xFFFFF800u), W[(e4).y & 0x7FFu], acc); \
    acc = fmaf(__uint_as_float((e4).z & 0xFFFFF800u), W[(e4).z & 0x7FFu], acc); \
    acc = fmaf(__uint_as_float((e4).w & 0xFFFFF800u), W[(e4).w & 0x7FFu], acc); \
} while (0)

extern "C" __global__ __launch_bounds__(TPB, 1)
void emd_iterate_56831007261025(uint8_t* __restrict__ wsb)
{
    __shared__ float    lu[NPT];          // 8 KB, SORTED (row-sort) space
    __shared__ float    lv[NPT];          // 8 KB, SORTED (col-sort) space
    __shared__ float    red[2][NWAVE];
    __shared__ uint32_t cflag[NWAVE];
    __shared__ uint32_t gmL[2][32];

    float* gu = (float*)(wsb + OFF_U);
    float* gv = (float*)(wsb + OFF_V);

    const int tid  = threadIdx.x;
    const int lane = tid & 63;
    const int wid  = tid >> 6;
    const int b    = blockIdx.x;
    const size_t ebase = (size_t)b * NPT * CAP;

    const uint32_t* rowE = (const uint32_t*)(wsb + OFF_ROWE) + ebase;
    const uint32_t* colE = (const uint32_t*)(wsb + OFF_COLE) + ebase;
    const uint32_t* gmax = (const uint32_t*)(wsb + OFF_GMAX);
    const uint16_t* prm  = (const uint16_t*)(wsb + OFF_PERM);

    if (tid < 32) {
        gmL[0][tid] = gmax[(size_t)b*32 + tid];
        gmL[1][tid] = gmax[256 + (size_t)b*32 + tid];
    }
    for (int i = tid; i < NPT; i += TPB) lv[i] = 1.0f;   // v0 = ones (perm-invariant)
    __syncthreads();

    // fixed lane->sorted-row assignment: pair small group (wid) with large group (31-wid)
    const int gA = wid, gB = 31 - wid;
    const int posA = gA*64 + lane, posB = gB*64 + lane;
    const int jAu = (__builtin_amdgcn_readfirstlane((int)gmL[0][gA]) + 3) >> 2;
    const int jBu = (__builtin_amdgcn_readfirstlane((int)gmL[0][gB]) + 3) >> 2;
    const int jAv = (__builtin_amdgcn_readfirstlane((int)gmL[1][gA]) + 3) >> 2;
    const int jBv = (__builtin_amdgcn_readfirstlane((int)gmL[1][gB]) + 3) >> 2;
    const uint32_t* rA = rowE + (size_t)posA * 4;
    const uint32_t* rB = rowE + (size_t)posB * 4;
    const uint32_t* cA = colE + (size_t)posA * 4;
    const uint32_t* cB = colE + (size_t)posB * 4;

    // cross-barrier prefetch of the first 2 j4-blocks (E is static; padding is zero => safe)
    uint4 pfA0 = ldE(rA, 0), pfA1 = ldE(rA, 1);
    uint4 pfB0 = ldE(rB, 0), pfB1 = ldE(rB, 1);

    for (int ph = 0; ph < 2*ITERS; ++ph) {
        const bool up = (ph & 1) == 0;                   // u-phase reads v, writes u
        const float* win  = up ? lv : lu;
        float*       wout = up ? lu : lv;
        const int jA = up ? jAu : jAv;
        const int jB = up ? jBu : jBv;
        const uint32_t* eA = up ? rA : cA;
        const uint32_t* eB = up ? rB : cB;

        // ---- fused dual-group scan: 4 accumulator chains, 4 loads in flight ----
        float aA = 0.0f, aA2 = 0.0f, aB = 0.0f, aB2 = 0.0f, rS = 0.0f, rS2 = 0.0f;
        FMA4(aA,  pfA0, win); FMA4(aA2, pfA1, win);
        FMA4(aB,  pfB0, win); FMA4(aB2, pfB1, win);

        const int jmin = (jA < jB) ? jA : jB;
        const int jbig = (jA > jB) ? jA : jB;
        int j4 = 2;
        for (; j4 + 1 < jmin; j4 += 2) {
            uint4 x0 = ldE(eA, j4),   y0 = ldE(eB, j4);
            uint4 x1 = ldE(eA, j4+1), y1 = ldE(eB, j4+1);
            FMA4(aA, x0, win); FMA4(aB, y0, win);
            FMA4(aA2, x1, win); FMA4(aB2, y1, win);
        }
        if (j4 < jmin) {
            uint4 x0 = ldE(eA, j4), y0 = ldE(eB, j4);
            FMA4(aA, x0, win); FMA4(aB, y0, win);
            ++j4;
        }
        const uint32_t* eL = (jA > jB) ? eA : eB;        // wave-uniform
        for (; j4 + 1 < jbig; j4 += 2) {
            uint4 x0 = ldE(eL, j4), x1 = ldE(eL, j4+1);
            FMA4(rS, x0, win); FMA4(rS2, x1, win);
        }
        if (j4 < jbig) { uint4 x0 = ldE(eL, j4); FMA4(rS, x0, win); }

        float accA = aA + aA2, accB = aB + aB2;
        float accR = rS + rS2;
        if (jA > jB) accA += accR; else accB += accR;

        // ---- issue next-phase prefetch early (hides L2 latency under epilogue+barrier) ----
        const uint32_t* nA = up ? cA : rA;
        const uint32_t* nB = up ? cB : rB;
        pfA0 = ldE(nA, 0); pfA1 = ldE(nA, 1);
        pfB0 = ldE(nB, 0); pfB1 = ldE(nB, 1);

        float oldA = 0.0f, oldB = 0.0f;
        if (!up) { oldA = wout[posA]; oldB = wout[posB]; }

        // Sw off the critical path: only needed for the C50 floor term
        float Sw;
        if (ph == 0) {
            Sw = (float)NPT;                             // sum(v0) = 2048 exactly
        } else {
            float s = 0.0f;
            #pragma unroll
            for (int w = 0; w < NWAVE; ++w) s += red[(ph - 1) & 1][w];
            Sw = s;
        }

        float valA = MUV / fmaxf(fmaf(C50, Sw, accA), EPS_DIVF);
        float valB = MUV / fmaxf(fmaf(C50, Sw, accB), EPS_DIVF);
        wout[posA] = valA;                               // sequential LDS write, conflict-free
        wout[posB] = valB;

        float psum = valA + valB;
        #pragma unroll
        for (int o = 32; o > 0; o >>= 1) psum += __shfl_down(psum, o, 64);
        if (lane == 0) red[ph & 1][wid] = psum;

        if (!up) {
            uint32_t chg = (__float_as_uint(valA) != __float_as_uint(oldA))
                         | (__float_as_uint(valB) != __float_as_uint(oldB));
            uint64_t m = __ballot(chg != 0u);
            if (lane == 0) cflag[wid] = (m != 0ull) ? 1u : 0u;
        }
        __syncthreads();
        if (!up) {
            uint32_t any = 0;
            #pragma unroll
            for (int w = 0; w < NWAVE; ++w) any |= cflag[w];
            if (!any) break;   // bitwise fixed point: remaining iterations identical
        }
    }

    // one-time permuted writeback: gu/gv in ORIGINAL order for the epilogue
    const uint16_t* prm0 = prm + (size_t)b*NPT;
    const uint16_t* prm1 = prm + (size_t)NB + (size_t)b*NPT;
    for (int i = tid; i < NPT; i += TPB) {
        gu[(size_t)b*NPT + prm0[i]] = lu[i];
        gv[(size_t)b*NPT + prm1[i]] = lv[i];
    }
}

// ========== kernel E: dense EMD epilogue: sum u*K*v*d ==========
extern "C" __global__ __launch_bounds__(TPB, 2)
void emd_epilogue_56831007261025(const uint8_t* __restrict__ wsb,
                                 float* __restrict__ out)
{
    __shared__ float4 tp[NPT];
    __shared__ float  lvv[NPT];
    __shared__ float  red[NWAVE];

    const float4* gspts = (const float4*)(wsb + OFF_SPTS);
    const float4* gtpts = (const float4*)(wsb + OFF_TPTS);
    const float*  gu    = (const float*) (wsb + OFF_U);
    const float*  gv    = (const float*) (wsb + OFF_V);

    const int tid  = threadIdx.x;
    const int lane = tid & 63;
    const int wid  = tid >> 6;
    const int b    = blockIdx.x >> 5;
    const int g    = blockIdx.x & 31;
    const size_t base = (size_t)b * NPT;

    for (int i = tid; i < NPT; i += TPB) {
        tp[i]  = gtpts[base + i];
        lvv[i] = gv[base + i];
    }
    __syncthreads();

    float wacc = 0.0f;
    for (int r = 0; r < 4; ++r) {
        size_t gi = base + g*64 + wid*4 + r;
        float4 sp   = gspts[gi];
        float  uval = gu[gi];
        float racc = 0.0f;
        for (int mb = 0; mb < NPT; mb += 64) {
            int m = mb + lane;
            float4 t = tp[m];
            float dx = sp.x - t.x, dy = sp.y - t.y, dz = sp.z - t.z;
            float d = sqrtf(dx*dx + dy*dy + dz*dz);
            float K = fmaxf(expf(-100.0f * d), C50);    // == exp(-min(100d,50))
            racc = fmaf(K * d, lvv[m], racc);
        }
        #pragma unroll
        for (int o = 32; o > 0; o >>= 1) racc += __shfl_down(racc, o, 64);
        if (lane == 0) wacc = fmaf(uval, racc, wacc);
    }
    if (lane == 0) red[wid] = wacc;
    __syncthreads();
    if (tid == 0) {
        float t = 0.0f;
        #pragma unroll
        for (int w = 0; w < NWAVE; ++w) t += red[w];
        atomicAdd(out, t * 0.125f);                     // mean over 8 batches
    }
}

extern "C" void kernel_launch(void* const* d_in, const int* in_sizes, int n_in,
                              void* d_out, int out_size, void* d_ws, size_t ws_size,
                              hipStream_t stream)
{
    const float* src = (const float*)d_in[0];
    const float* tgt = (const float*)d_in[1];
    float* out = (float*)d_out;
    uint8_t* ws = (uint8_t*)d_ws;

    emd_count_56831007261025  <<<dim3(256), dim3(TPB), 0, stream>>>(src, tgt, ws, out);
    emd_sort_56831007261025   <<<dim3(16),  dim3(256), 0, stream>>>(ws);
    emd_build_56831007261025  <<<dim3(256), dim3(TPB), 0, stream>>>(ws);
    emd_iterate_56831007261025<<<dim3(8),   dim3(TPB), 0, stream>>>(ws);
    emd_epilogue_56831007261025<<<dim3(256), dim3(TPB), 0, stream>>>(ws, out);
}